// Round 11
// baseline (294.400 us; speedup 1.0000x reference)
//
#include <hip/hip_runtime.h>
#include <math.h>

#define NHEADS 4
#define HDIM 32
#define F 128     // Fin == H*C == 128 for both layers
#define ACH 16384 // edges per block in bucket pass A

typedef __attribute__((ext_vector_type(8))) short bf16x8;
typedef __attribute__((ext_vector_type(4))) float f32x4;

__device__ __forceinline__ float lrelu(float v) { return v > 0.f ? v : 0.2f * v; }

__device__ __forceinline__ unsigned short cvt_bf16(float f) {
    unsigned u = __float_as_uint(f);
    u += 0x7fffu + ((u >> 16) & 1u);     // round-to-nearest-even
    return (unsigned short)(u >> 16);
}

// ---------------- W pre-pack into MFMA B-fragment order (bf16) ----------------
// ct==8 is the fused-alpha fragment: cols 0-3 = (W @ a_src)[k][head],
// cols 4-7 = (W @ a_dst)[k][head-4], cols 8-15 = 0.
__global__ void k_packW(const float* __restrict__ W, const float* __restrict__ a_src,
                        const float* __restrict__ a_dst, short* __restrict__ Wb) {
    int idx = blockIdx.x * 256 + threadIdx.x;
    if (idx >= 36 * 512) return;
    int j    = idx & 7;
    int lane = (idx >> 3) & 63;
    int frag = idx >> 9;
    int kk = frag / 9, ct = frag % 9;
    int k = kk * 32 + (lane >> 4) * 8 + j;
    int col = lane & 15;
    float val;
    if (ct < 8) {
        val = W[k * F + ct * 16 + col];
    } else if (col < 8) {
        int head = col & 3;
        const float* av = (col < 4) ? a_src : a_dst;
        float sum = 0.f;
        #pragma unroll 8
        for (int c = 0; c < HDIM; ++c)
            sum += W[k * F + head * HDIM + c] * av[head * HDIM + c];
        val = sum;
    } else {
        val = 0.f;
    }
    Wb[idx] = (short)cvt_bf16(val);
}

// ---------------- MFMA GEMM: h = x @ W, fused alpha, bf16 h out ---------------
template<bool ABF16>
__global__ __launch_bounds__(256) void k_gemm_mfma(
    const void* __restrict__ xv, const short* __restrict__ Wb,
    unsigned short* __restrict__ hbf, float* __restrict__ as_out,
    float* __restrict__ ad_out, int N)
{
    const int wid  = threadIdx.x >> 6;
    const int lane = threadIdx.x & 63;
    const int rowbase = blockIdx.x * 64 + wid * 16;
    const int row  = rowbase + (lane & 15);
    const int rowc = min(row, N - 1);
    const int col = lane & 15;

    f32x4 acc[9] = {};
    #pragma unroll
    for (int kk = 0; kk < 4; ++kk) {
        bf16x8 a;
        if constexpr (ABF16) {
            const unsigned short* xr =
                (const unsigned short*)xv + (size_t)rowc * F + (lane >> 4) * 8;
            a = *(const bf16x8*)(xr + kk * 32);
        } else {
            const float* xr = (const float*)xv + (size_t)rowc * F + (lane >> 4) * 8;
            float4 xa = *(const float4*)(xr + kk * 32);
            float4 xb = *(const float4*)(xr + kk * 32 + 4);
            a[0] = cvt_bf16(xa.x); a[1] = cvt_bf16(xa.y);
            a[2] = cvt_bf16(xa.z); a[3] = cvt_bf16(xa.w);
            a[4] = cvt_bf16(xb.x); a[5] = cvt_bf16(xb.y);
            a[6] = cvt_bf16(xb.z); a[7] = cvt_bf16(xb.w);
        }
        const bf16x8* bp = (const bf16x8*)(Wb + (size_t)(kk * 9) * 512 + lane * 8);
        #pragma unroll
        for (int ct = 0; ct < 9; ++ct) {
            bf16x8 b = bp[ct * 64];
            acc[ct] = __builtin_amdgcn_mfma_f32_16x16x32_bf16(a, b, acc[ct], 0, 0, 0);
        }
    }

    const int r0 = rowbase + (lane >> 4) * 4;
    #pragma unroll
    for (int i = 0; i < 4; ++i) {
        int r = r0 + i;
        if (r < N) {
            #pragma unroll
            for (int ct = 0; ct < 8; ++ct)
                hbf[(size_t)r * F + ct * 16 + col] = cvt_bf16(acc[ct][i]);
            if (col < 4)       as_out[r * NHEADS + col]     = acc[8][i];
            else if (col < 8)  ad_out[r * NHEADS + col - 4] = acc[8][i];
        }
    }
}

// ============ CSR build via coarse buckets (no global atomics) ============
// bucket = dst >> 8 (256 nodes each). Pass A: per-block LDS histogram ->
// parallel column scan -> block-private contiguous write regions -> epairs
// bucket-major. Pass B (k_bfinal): one block per bucket computes deg,
// rowptr (bbase + in-block scan) and the final CSR scatter in one kernel.

// A1: per-block histogram over nbuc buckets
__global__ __launch_bounds__(256) void k_bhist(
    const int* __restrict__ src, const int* __restrict__ dst,
    int* __restrict__ bha, int nbuc, int E, int TOT)
{
    __shared__ int hist[512];
    int t = threadIdx.x;
    hist[t] = 0; hist[t + 256] = 0;
    __syncthreads();
    int base = blockIdx.x * ACH;
    #pragma unroll
    for (int k = 0; k < ACH / 256; ++k) {
        int i = base + k * 256 + t;
        if (i < TOT) {
            int d = (i < E) ? dst[i] : (i - E);
            atomicAdd(&hist[d >> 8], 1);
        }
    }
    __syncthreads();
    if (t < nbuc)        bha[(size_t)blockIdx.x * nbuc + t] = hist[t];
    if (t + 256 < nbuc)  bha[(size_t)blockIdx.x * nbuc + t + 256] = hist[t + 256];
}

// Scan P1: per-bucket (column) exclusive prefix over the nab A-blocks.
__global__ __launch_bounds__(256) void k_bscan1(
    int* __restrict__ bha, int* __restrict__ btot, int nbuc, int nab)
{
    int t = blockIdx.x * 256 + threadIdx.x;
    if (t >= nbuc) return;
    int run = 0;
    int j = 0;
    for (; j + 4 <= nab; j += 4) {
        int v0 = bha[(size_t)(j + 0) * nbuc + t];
        int v1 = bha[(size_t)(j + 1) * nbuc + t];
        int v2 = bha[(size_t)(j + 2) * nbuc + t];
        int v3 = bha[(size_t)(j + 3) * nbuc + t];
        bha[(size_t)(j + 0) * nbuc + t] = run; run += v0;
        bha[(size_t)(j + 1) * nbuc + t] = run; run += v1;
        bha[(size_t)(j + 2) * nbuc + t] = run; run += v2;
        bha[(size_t)(j + 3) * nbuc + t] = run; run += v3;
    }
    for (; j < nab; ++j) {
        int v = bha[(size_t)j * nbuc + t];
        bha[(size_t)j * nbuc + t] = run; run += v;
    }
    btot[t] = run;
}

// Scan P2: exclusive scan of bucket totals (nbuc <= 512), single block
__global__ __launch_bounds__(512) void k_bscan2(
    const int* __restrict__ btot, int* __restrict__ bbase, int nbuc)
{
    __shared__ int sh[512];
    int t = threadIdx.x;
    int v = (t < nbuc) ? btot[t] : 0;
    sh[t] = v;
    __syncthreads();
    for (int off = 1; off < 512; off <<= 1) {
        int u = (t >= off) ? sh[t - off] : 0;
        __syncthreads();
        sh[t] += u;
        __syncthreads();
    }
    if (t < nbuc) {
        bbase[t] = sh[t] - v;
        if (t == nbuc - 1) bbase[nbuc] = sh[t];
    }
}

// Scan P3: add bucket bases back into per-block offsets (fully parallel)
__global__ __launch_bounds__(256) void k_bscan3(
    int* __restrict__ bha, const int* __restrict__ bbase, int nbuc, int total)
{
    int i = blockIdx.x * 256 + threadIdx.x;
    if (i < total) bha[i] += bbase[i % nbuc];
}

// A2: scatter (src,dst) pairs into bucket-major array, block-private regions
__global__ __launch_bounds__(256) void k_bscatter(
    const int* __restrict__ src, const int* __restrict__ dst,
    const int* __restrict__ bha, int2* __restrict__ epairs,
    int nbuc, int E, int TOT)
{
    __shared__ int cur[512];
    int t = threadIdx.x;
    if (t < nbuc)       cur[t] = bha[(size_t)blockIdx.x * nbuc + t];
    if (t + 256 < nbuc) cur[t + 256] = bha[(size_t)blockIdx.x * nbuc + t + 256];
    __syncthreads();
    int base = blockIdx.x * ACH;
    #pragma unroll
    for (int k = 0; k < ACH / 256; ++k) {
        int i = base + k * 256 + t;
        if (i < TOT) {
            int s, d;
            if (i < E) { s = src[i]; d = dst[i]; } else { s = d = i - E; }
            int pos = atomicAdd(&cur[d >> 8], 1);
            epairs[pos] = make_int2(s, d);
        }
    }
}

// B (fused): per-bucket deg + rowptr (bbase + LDS scan) + final CSR scatter
__global__ __launch_bounds__(256) void k_bfinal(
    const int2* __restrict__ epairs, const int* __restrict__ bbase,
    int* __restrict__ deg, int* __restrict__ rowptr, int* __restrict__ ssrc,
    int N, int nbuc)
{
    __shared__ int hist[256];
    __shared__ int sh[256];
    __shared__ int cur[256];
    int t = threadIdx.x;
    hist[t] = 0;
    __syncthreads();
    int s0 = bbase[blockIdx.x], s1 = bbase[blockIdx.x + 1];
    for (int i = s0 + t; i < s1; i += 256)
        atomicAdd(&hist[epairs[i].y & 255], 1);
    __syncthreads();
    int h = hist[t];
    sh[t] = h;
    __syncthreads();
    for (int off = 1; off < 256; off <<= 1) {
        int u = (t >= off) ? sh[t - off] : 0;
        __syncthreads();
        sh[t] += u;
        __syncthreads();
    }
    int node = blockIdx.x * 256 + t;
    int excl = s0 + sh[t] - h;
    cur[t] = excl;
    if (node < N) {
        deg[node] = h;
        rowptr[node] = excl;
    }
    if (node == 0) rowptr[N] = bbase[nbuc];
    __syncthreads();
    for (int i = s0 + t; i < s1; i += 256) {
        int2 p = epairs[i];
        int pos = atomicAdd(&cur[p.y & 255], 1);
        ssrc[pos] = p.x;
    }
}

// ------------- degree sort: block-local counting sort (no global atomics) ------
__global__ __launch_bounds__(256) void k_sort_hist(
    const int* __restrict__ deg, int* __restrict__ bh, int N)
{
    __shared__ int hist[256];
    int t = threadIdx.x;
    hist[t] = 0;
    __syncthreads();
    int base = blockIdx.x * 1024;
    #pragma unroll
    for (int g = 0; g < 4; ++g) {
        int i = base + g * 256 + t;
        if (i < N) atomicAdd(&hist[min(deg[i], 255)], 1);
    }
    __syncthreads();
    bh[blockIdx.x * 256 + t] = hist[t];
}

__global__ __launch_bounds__(256) void k_sort_off(int* __restrict__ bh, int nb)
{
    int t = threadIdx.x;
    int run = 0;
    for (int j = 0; j < nb; ++j) {
        int v = bh[j * 256 + t];
        bh[j * 256 + t] = run;
        run += v;
    }
    __shared__ int sh[256];
    int tot = run;
    sh[t] = tot;
    __syncthreads();
    for (int off = 1; off < 256; off <<= 1) {
        int u = (t >= off) ? sh[t - off] : 0;
        __syncthreads();
        sh[t] += u;
        __syncthreads();
    }
    int bucket_base = sh[t] - tot;   // exclusive
    for (int j = 0; j < nb; ++j)
        bh[j * 256 + t] += bucket_base;
}

__global__ __launch_bounds__(256) void k_sort_scatter(
    const int* __restrict__ deg, const int* __restrict__ bh,
    int* __restrict__ order, int N)
{
    __shared__ int cur[256];
    int t = threadIdx.x;
    cur[t] = bh[blockIdx.x * 256 + t];
    __syncthreads();
    int base = blockIdx.x * 1024;
    #pragma unroll
    for (int g = 0; g < 4; ++g) {
        int i = base + g * 256 + t;
        if (i < N) {
            int pos = atomicAdd(&cur[min(deg[i], 255)], 1);
            order[pos] = i;
        }
    }
}

// ---------------- single-pass softmax + weighted aggregation ----------------
// 16 lanes per node (degree-sorted order), 4 nodes per wave. 16 edges batched
// per iteration (all gathers issued back-to-back -> 16-deep MLP); tail edges
// index-clamped (duplicate gathers hit cache) and predicated out of the math.
template<bool OUTBF16>
__global__ __launch_bounds__(256) void k_aggregate(
    const int* __restrict__ rowptr, const int* __restrict__ ssrc,
    const int* __restrict__ order,
    const float* __restrict__ as, const float* __restrict__ ad,
    const unsigned short* __restrict__ hbf, const float* __restrict__ bias,
    void* __restrict__ outv, int N)
{
    int gi = (blockIdx.x * 256 + threadIdx.x) >> 4;
    if (gi >= N) return;
    const int node  = order[gi];
    const int l16   = threadIdx.x & 15;
    const int hb    = l16 >> 2;
    const int c0    = l16 * 8;
    const int start = rowptr[node], end = rowptr[node + 1];
    const float adB = ad[node * NHEADS + hb];

    float a0=0.f,a1=0.f,a2=0.f,a3=0.f,a4=0.f,a5=0.f,a6=0.f,a7=0.f;
    float dacc = 0.f;
    for (int base = start; base < end; base += 16) {
        int   sj[16];
        float fj[16];
        uint4 hj[16];
        #pragma unroll
        for (int j = 0; j < 16; ++j)
            sj[j] = ssrc[min(base + j, end - 1)];
        #pragma unroll
        for (int j = 0; j < 16; ++j)
            fj[j] = as[sj[j] * NHEADS + hb];
        #pragma unroll
        for (int j = 0; j < 16; ++j)
            hj[j] = *(const uint4*)(hbf + (size_t)sj[j] * F + c0);
        #pragma unroll
        for (int j = 0; j < 16; ++j) {
            float ex = (base + j < end) ? __expf(lrelu(fj[j] + adB)) : 0.f;
            dacc += ex;
            a0 = fmaf(ex, __uint_as_float(hj[j].x << 16),         a0);
            a1 = fmaf(ex, __uint_as_float(hj[j].x & 0xffff0000u), a1);
            a2 = fmaf(ex, __uint_as_float(hj[j].y << 16),         a2);
            a3 = fmaf(ex, __uint_as_float(hj[j].y & 0xffff0000u), a3);
            a4 = fmaf(ex, __uint_as_float(hj[j].z << 16),         a4);
            a5 = fmaf(ex, __uint_as_float(hj[j].z & 0xffff0000u), a5);
            a6 = fmaf(ex, __uint_as_float(hj[j].w << 16),         a6);
            a7 = fmaf(ex, __uint_as_float(hj[j].w & 0xffff0000u), a7);
        }
    }
    float inv = 1.f / dacc;
    float v[8] = {a0,a1,a2,a3,a4,a5,a6,a7};
    #pragma unroll
    for (int k = 0; k < 8; ++k) {
        float t = v[k] * inv + bias[c0 + k];
        v[k] = t > 0.f ? t : expm1f(t);
    }
    if (OUTBF16) {
        unsigned r0 = (unsigned)cvt_bf16(v[0]) | ((unsigned)cvt_bf16(v[1]) << 16);
        unsigned r1 = (unsigned)cvt_bf16(v[2]) | ((unsigned)cvt_bf16(v[3]) << 16);
        unsigned r2 = (unsigned)cvt_bf16(v[4]) | ((unsigned)cvt_bf16(v[5]) << 16);
        unsigned r3 = (unsigned)cvt_bf16(v[6]) | ((unsigned)cvt_bf16(v[7]) << 16);
        uint4 o = {r0, r1, r2, r3};
        *(uint4*)((unsigned short*)outv + (size_t)node * F + c0) = o;
    } else {
        float4 o0 = {v[0], v[1], v[2], v[3]};
        float4 o1 = {v[4], v[5], v[6], v[7]};
        float* op = (float*)outv + (size_t)node * F + c0;
        *(float4*)op       = o0;
        *(float4*)(op + 4) = o1;
    }
}

extern "C" void kernel_launch(void* const* d_in, const int* in_sizes, int n_in,
                              void* d_out, int out_size, void* d_ws, size_t ws_size,
                              hipStream_t stream)
{
    const float* x      = (const float*)d_in[0];
    const int*   eidx   = (const int*)d_in[1];
    const float* W1     = (const float*)d_in[2];
    const float* a_src1 = (const float*)d_in[3];
    const float* a_dst1 = (const float*)d_in[4];
    const float* b1     = (const float*)d_in[5];
    const float* W2     = (const float*)d_in[6];
    const float* a_src2 = (const float*)d_in[7];
    const float* a_dst2 = (const float*)d_in[8];
    const float* b2     = (const float*)d_in[9];

    const int N = in_sizes[0] / F;
    const int E = in_sizes[1] / 2;
    const int TOT = E + N;
    const int* src = eidx;
    const int* dst = eidx + E;

    const int nbuc = (N + 255) / 256;        // coarse buckets (dst>>8)
    const int nab  = (TOT + ACH - 1) / ACH;  // pass-A blocks
    const int nb   = (N + 1023) / 1024;      // degree-sort blocks

    // workspace layout (epairs first for 8B/16B alignment)
    int2* epairs = (int2*)d_ws;                            // TOT
    unsigned short* hbf    = (unsigned short*)(epairs + TOT);  // N*F bf16
    unsigned short* out1bf = hbf + (size_t)N * F;          // N*F bf16
    float* as = (float*)(out1bf + (size_t)N * F);          // N*4
    float* ad = as + (size_t)N * NHEADS;                   // N*4
    int* deg    = (int*)(ad + (size_t)N * NHEADS);         // N
    int* rowptr = deg + N;                                 // N+1
    int* ssrc   = rowptr + N + 1;                          // TOT
    int* order  = ssrc + TOT;                              // N
    int* bh     = order + N;                               // nb*256
    int* bha    = bh + (size_t)nb * 256;                   // nab*nbuc
    int* btot   = bha + (size_t)nab * nbuc;                // nbuc
    int* bbase  = btot + nbuc;                             // nbuc+1
    short* Wb1  = (short*)(((uintptr_t)(bbase + nbuc + 1) + 15) & ~(uintptr_t)15);
    short* Wb2  = Wb1 + 36 * 512;

    const int gemmBlocks = (N + 63) / 64;
    const int aggBlocks  = (N + 15) / 16;

    // ---- W pre-pack ----
    k_packW<<<72, 256, 0, stream>>>(W1, a_src1, a_dst1, Wb1);
    k_packW<<<72, 256, 0, stream>>>(W2, a_src2, a_dst2, Wb2);

    // ---- CSR build via coarse buckets ----
    k_bhist<<<nab, 256, 0, stream>>>(src, dst, bha, nbuc, E, TOT);
    k_bscan1<<<(nbuc + 255) / 256, 256, 0, stream>>>(bha, btot, nbuc, nab);
    k_bscan2<<<1, 512, 0, stream>>>(btot, bbase, nbuc);
    k_bscan3<<<(nab * nbuc + 255) / 256, 256, 0, stream>>>(bha, bbase, nbuc, nab * nbuc);
    k_bscatter<<<nab, 256, 0, stream>>>(src, dst, bha, epairs, nbuc, E, TOT);
    k_bfinal<<<nbuc, 256, 0, stream>>>(epairs, bbase, deg, rowptr, ssrc, N, nbuc);

    // ---- degree sort ----
    k_sort_hist<<<nb, 256, 0, stream>>>(deg, bh, N);
    k_sort_off<<<1, 256, 0, stream>>>(bh, nb);
    k_sort_scatter<<<nb, 256, 0, stream>>>(deg, bh, order, N);

    // ---- layer 1: x (f32) -> out1bf (bf16) ----
    k_gemm_mfma<false><<<gemmBlocks, 256, 0, stream>>>(x, Wb1, hbf, as, ad, N);
    k_aggregate<true><<<aggBlocks, 256, 0, stream>>>(rowptr, ssrc, order, as, ad, hbf, b1, out1bf, N);

    // ---- layer 2: out1bf (bf16) -> d_out (f32) ----
    k_gemm_mfma<true><<<gemmBlocks, 256, 0, stream>>>(out1bf, Wb2, hbf, as, ad, N);
    k_aggregate<false><<<aggBlocks, 256, 0, stream>>>(rowptr, ssrc, order, as, ad, hbf, b2, d_out, N);
}

// Round 12
// 289.918 us; speedup vs baseline: 1.0155x; 1.0155x over previous
//
#include <hip/hip_runtime.h>
#include <math.h>

#define NHEADS 4
#define HDIM 32
#define F 128     // Fin == H*C == 128 for both layers
#define ACH 16384 // edges per block in bucket pass A

typedef __attribute__((ext_vector_type(8))) short bf16x8;
typedef __attribute__((ext_vector_type(4))) float f32x4;

__device__ __forceinline__ float lrelu(float v) { return v > 0.f ? v : 0.2f * v; }

__device__ __forceinline__ unsigned short cvt_bf16(float f) {
    unsigned u = __float_as_uint(f);
    u += 0x7fffu + ((u >> 16) & 1u);     // round-to-nearest-even
    return (unsigned short)(u >> 16);
}

// ---------------- W pre-pack into MFMA B-fragment order (bf16) ----------------
// ct==8 is the fused-alpha fragment: cols 0-3 = (W @ a_src)[k][head],
// cols 4-7 = (W @ a_dst)[k][head-4], cols 8-15 = 0.
__global__ void k_packW(const float* __restrict__ W, const float* __restrict__ a_src,
                        const float* __restrict__ a_dst, short* __restrict__ Wb) {
    int idx = blockIdx.x * 256 + threadIdx.x;
    if (idx >= 36 * 512) return;
    int j    = idx & 7;
    int lane = (idx >> 3) & 63;
    int frag = idx >> 9;
    int kk = frag / 9, ct = frag % 9;
    int k = kk * 32 + (lane >> 4) * 8 + j;
    int col = lane & 15;
    float val;
    if (ct < 8) {
        val = W[k * F + ct * 16 + col];
    } else if (col < 8) {
        int head = col & 3;
        const float* av = (col < 4) ? a_src : a_dst;
        float sum = 0.f;
        #pragma unroll 8
        for (int c = 0; c < HDIM; ++c)
            sum += W[k * F + head * HDIM + c] * av[head * HDIM + c];
        val = sum;
    } else {
        val = 0.f;
    }
    Wb[idx] = (short)cvt_bf16(val);
}

// ---------------- MFMA GEMM: h = x @ W, fused alpha, bf16 h out ---------------
template<bool ABF16>
__global__ __launch_bounds__(256) void k_gemm_mfma(
    const void* __restrict__ xv, const short* __restrict__ Wb,
    unsigned short* __restrict__ hbf, float* __restrict__ as_out,
    float* __restrict__ ad_out, int N)
{
    const int wid  = threadIdx.x >> 6;
    const int lane = threadIdx.x & 63;
    const int rowbase = blockIdx.x * 64 + wid * 16;
    const int row  = rowbase + (lane & 15);
    const int rowc = min(row, N - 1);
    const int col = lane & 15;

    f32x4 acc[9] = {};
    #pragma unroll
    for (int kk = 0; kk < 4; ++kk) {
        bf16x8 a;
        if constexpr (ABF16) {
            const unsigned short* xr =
                (const unsigned short*)xv + (size_t)rowc * F + (lane >> 4) * 8;
            a = *(const bf16x8*)(xr + kk * 32);
        } else {
            const float* xr = (const float*)xv + (size_t)rowc * F + (lane >> 4) * 8;
            float4 xa = *(const float4*)(xr + kk * 32);
            float4 xb = *(const float4*)(xr + kk * 32 + 4);
            a[0] = cvt_bf16(xa.x); a[1] = cvt_bf16(xa.y);
            a[2] = cvt_bf16(xa.z); a[3] = cvt_bf16(xa.w);
            a[4] = cvt_bf16(xb.x); a[5] = cvt_bf16(xb.y);
            a[6] = cvt_bf16(xb.z); a[7] = cvt_bf16(xb.w);
        }
        const bf16x8* bp = (const bf16x8*)(Wb + (size_t)(kk * 9) * 512 + lane * 8);
        #pragma unroll
        for (int ct = 0; ct < 9; ++ct) {
            bf16x8 b = bp[ct * 64];
            acc[ct] = __builtin_amdgcn_mfma_f32_16x16x32_bf16(a, b, acc[ct], 0, 0, 0);
        }
    }

    const int r0 = rowbase + (lane >> 4) * 4;
    #pragma unroll
    for (int i = 0; i < 4; ++i) {
        int r = r0 + i;
        if (r < N) {
            #pragma unroll
            for (int ct = 0; ct < 8; ++ct)
                hbf[(size_t)r * F + ct * 16 + col] = cvt_bf16(acc[ct][i]);
            if (col < 4)       as_out[r * NHEADS + col]     = acc[8][i];
            else if (col < 8)  ad_out[r * NHEADS + col - 4] = acc[8][i];
        }
    }
}

// ============ CSR build via coarse buckets (no global atomics) ============
// bucket = dst >> 8 (256 nodes each). Edge record packed into one uint:
// (src << 8) | (dst & 255) -- bucket id is implicit in position.

// A1: per-block histogram over nbuc buckets
__global__ __launch_bounds__(256) void k_bhist(
    const int* __restrict__ src, const int* __restrict__ dst,
    int* __restrict__ bha, int nbuc, int E, int TOT)
{
    __shared__ int hist[512];
    int t = threadIdx.x;
    hist[t] = 0; hist[t + 256] = 0;
    __syncthreads();
    int base = blockIdx.x * ACH;
    #pragma unroll
    for (int k = 0; k < ACH / 256; ++k) {
        int i = base + k * 256 + t;
        if (i < TOT) {
            int d = (i < E) ? dst[i] : (i - E);
            atomicAdd(&hist[d >> 8], 1);
        }
    }
    __syncthreads();
    if (t < nbuc)        bha[(size_t)blockIdx.x * nbuc + t] = hist[t];
    if (t + 256 < nbuc)  bha[(size_t)blockIdx.x * nbuc + t + 256] = hist[t + 256];
}

// Scan P1: per-bucket (column) exclusive prefix over the nab A-blocks.
__global__ __launch_bounds__(256) void k_bscan1(
    int* __restrict__ bha, int* __restrict__ btot, int nbuc, int nab)
{
    int t = blockIdx.x * 256 + threadIdx.x;
    if (t >= nbuc) return;
    int run = 0;
    int j = 0;
    for (; j + 4 <= nab; j += 4) {
        int v0 = bha[(size_t)(j + 0) * nbuc + t];
        int v1 = bha[(size_t)(j + 1) * nbuc + t];
        int v2 = bha[(size_t)(j + 2) * nbuc + t];
        int v3 = bha[(size_t)(j + 3) * nbuc + t];
        bha[(size_t)(j + 0) * nbuc + t] = run; run += v0;
        bha[(size_t)(j + 1) * nbuc + t] = run; run += v1;
        bha[(size_t)(j + 2) * nbuc + t] = run; run += v2;
        bha[(size_t)(j + 3) * nbuc + t] = run; run += v3;
    }
    for (; j < nab; ++j) {
        int v = bha[(size_t)j * nbuc + t];
        bha[(size_t)j * nbuc + t] = run; run += v;
    }
    btot[t] = run;
}

// Scan P2: exclusive scan of bucket totals (nbuc <= 512), single block
__global__ __launch_bounds__(512) void k_bscan2(
    const int* __restrict__ btot, int* __restrict__ bbase, int nbuc)
{
    __shared__ int sh[512];
    int t = threadIdx.x;
    int v = (t < nbuc) ? btot[t] : 0;
    sh[t] = v;
    __syncthreads();
    for (int off = 1; off < 512; off <<= 1) {
        int u = (t >= off) ? sh[t - off] : 0;
        __syncthreads();
        sh[t] += u;
        __syncthreads();
    }
    if (t < nbuc) {
        bbase[t] = sh[t] - v;
        if (t == nbuc - 1) bbase[nbuc] = sh[t];
    }
}

// Scan P3: add bucket bases back into per-block offsets (fully parallel)
__global__ __launch_bounds__(256) void k_bscan3(
    int* __restrict__ bha, const int* __restrict__ bbase, int nbuc, int total)
{
    int i = blockIdx.x * 256 + threadIdx.x;
    if (i < total) bha[i] += bbase[i % nbuc];
}

// A2: scatter packed edges into bucket-major array, block-private regions
__global__ __launch_bounds__(256) void k_bscatter(
    const int* __restrict__ src, const int* __restrict__ dst,
    const int* __restrict__ bha, unsigned* __restrict__ epack,
    int nbuc, int E, int TOT)
{
    __shared__ int cur[512];
    int t = threadIdx.x;
    if (t < nbuc)       cur[t] = bha[(size_t)blockIdx.x * nbuc + t];
    if (t + 256 < nbuc) cur[t + 256] = bha[(size_t)blockIdx.x * nbuc + t + 256];
    __syncthreads();
    int base = blockIdx.x * ACH;
    #pragma unroll
    for (int k = 0; k < ACH / 256; ++k) {
        int i = base + k * 256 + t;
        if (i < TOT) {
            int s, d;
            if (i < E) { s = src[i]; d = dst[i]; } else { s = d = i - E; }
            int pos = atomicAdd(&cur[d >> 8], 1);
            epack[pos] = ((unsigned)s << 8) | (unsigned)(d & 255);
        }
    }
}

// B (fused): per-bucket deg + rowptr (bbase + LDS scan) + final CSR scatter
__global__ __launch_bounds__(256) void k_bfinal(
    const unsigned* __restrict__ epack, const int* __restrict__ bbase,
    int* __restrict__ deg, int* __restrict__ rowptr, int* __restrict__ ssrc,
    int N, int nbuc)
{
    __shared__ int hist[256];
    __shared__ int sh[256];
    __shared__ int cur[256];
    int t = threadIdx.x;
    hist[t] = 0;
    __syncthreads();
    int s0 = bbase[blockIdx.x], s1 = bbase[blockIdx.x + 1];
    for (int i = s0 + t; i < s1; i += 256)
        atomicAdd(&hist[epack[i] & 255u], 1);
    __syncthreads();
    int h = hist[t];
    sh[t] = h;
    __syncthreads();
    for (int off = 1; off < 256; off <<= 1) {
        int u = (t >= off) ? sh[t - off] : 0;
        __syncthreads();
        sh[t] += u;
        __syncthreads();
    }
    int node = blockIdx.x * 256 + t;
    int excl = s0 + sh[t] - h;
    cur[t] = excl;
    if (node < N) {
        deg[node] = h;
        rowptr[node] = excl;
    }
    if (node == 0) rowptr[N] = bbase[nbuc];
    __syncthreads();
    for (int i = s0 + t; i < s1; i += 256) {
        unsigned p = epack[i];
        int pos = atomicAdd(&cur[p & 255u], 1);
        ssrc[pos] = (int)(p >> 8);
    }
}

// ------------- degree sort: block-local counting sort (no global atomics) ------
__global__ __launch_bounds__(256) void k_sort_hist(
    const int* __restrict__ deg, int* __restrict__ bh, int N)
{
    __shared__ int hist[256];
    int t = threadIdx.x;
    hist[t] = 0;
    __syncthreads();
    int base = blockIdx.x * 1024;
    #pragma unroll
    for (int g = 0; g < 4; ++g) {
        int i = base + g * 256 + t;
        if (i < N) atomicAdd(&hist[min(deg[i], 255)], 1);
    }
    __syncthreads();
    bh[blockIdx.x * 256 + t] = hist[t];
}

__global__ __launch_bounds__(256) void k_sort_off(int* __restrict__ bh, int nb)
{
    int t = threadIdx.x;
    int run = 0;
    for (int j = 0; j < nb; ++j) {
        int v = bh[j * 256 + t];
        bh[j * 256 + t] = run;
        run += v;
    }
    __shared__ int sh[256];
    int tot = run;
    sh[t] = tot;
    __syncthreads();
    for (int off = 1; off < 256; off <<= 1) {
        int u = (t >= off) ? sh[t - off] : 0;
        __syncthreads();
        sh[t] += u;
        __syncthreads();
    }
    int bucket_base = sh[t] - tot;   // exclusive
    for (int j = 0; j < nb; ++j)
        bh[j * 256 + t] += bucket_base;
}

__global__ __launch_bounds__(256) void k_sort_scatter(
    const int* __restrict__ deg, const int* __restrict__ bh,
    int* __restrict__ order, int N)
{
    __shared__ int cur[256];
    int t = threadIdx.x;
    cur[t] = bh[blockIdx.x * 256 + t];
    __syncthreads();
    int base = blockIdx.x * 1024;
    #pragma unroll
    for (int g = 0; g < 4; ++g) {
        int i = base + g * 256 + t;
        if (i < N) {
            int pos = atomicAdd(&cur[min(deg[i], 255)], 1);
            order[pos] = i;
        }
    }
}

// ---------------- single-pass softmax + weighted aggregation ----------------
// 16 lanes per node (degree-sorted order), 4 nodes per wave. 8 edges batched
// per iteration (proven sweet spot: 44 VGPR, ~46% occupancy); tail edges
// index-clamped (duplicate gathers hit cache) and predicated out of the math.
template<bool OUTBF16>
__global__ __launch_bounds__(256) void k_aggregate(
    const int* __restrict__ rowptr, const int* __restrict__ ssrc,
    const int* __restrict__ order,
    const float* __restrict__ as, const float* __restrict__ ad,
    const unsigned short* __restrict__ hbf, const float* __restrict__ bias,
    void* __restrict__ outv, int N)
{
    int gi = (blockIdx.x * 256 + threadIdx.x) >> 4;
    if (gi >= N) return;
    const int node  = order[gi];
    const int l16   = threadIdx.x & 15;
    const int hb    = l16 >> 2;
    const int c0    = l16 * 8;
    const int start = rowptr[node], end = rowptr[node + 1];
    const float adB = ad[node * NHEADS + hb];

    float a0=0.f,a1=0.f,a2=0.f,a3=0.f,a4=0.f,a5=0.f,a6=0.f,a7=0.f;
    float dacc = 0.f;
    for (int base = start; base < end; base += 8) {
        int   sj[8];
        float fj[8];
        uint4 hj[8];
        #pragma unroll
        for (int j = 0; j < 8; ++j)
            sj[j] = ssrc[min(base + j, end - 1)];
        #pragma unroll
        for (int j = 0; j < 8; ++j)
            fj[j] = as[sj[j] * NHEADS + hb];
        #pragma unroll
        for (int j = 0; j < 8; ++j)
            hj[j] = *(const uint4*)(hbf + (size_t)sj[j] * F + c0);
        #pragma unroll
        for (int j = 0; j < 8; ++j) {
            float ex = (base + j < end) ? __expf(lrelu(fj[j] + adB)) : 0.f;
            dacc += ex;
            a0 = fmaf(ex, __uint_as_float(hj[j].x << 16),         a0);
            a1 = fmaf(ex, __uint_as_float(hj[j].x & 0xffff0000u), a1);
            a2 = fmaf(ex, __uint_as_float(hj[j].y << 16),         a2);
            a3 = fmaf(ex, __uint_as_float(hj[j].y & 0xffff0000u), a3);
            a4 = fmaf(ex, __uint_as_float(hj[j].z << 16),         a4);
            a5 = fmaf(ex, __uint_as_float(hj[j].z & 0xffff0000u), a5);
            a6 = fmaf(ex, __uint_as_float(hj[j].w << 16),         a6);
            a7 = fmaf(ex, __uint_as_float(hj[j].w & 0xffff0000u), a7);
        }
    }
    float inv = 1.f / dacc;
    float v[8] = {a0,a1,a2,a3,a4,a5,a6,a7};
    #pragma unroll
    for (int k = 0; k < 8; ++k) {
        float t = v[k] * inv + bias[c0 + k];
        v[k] = t > 0.f ? t : expm1f(t);
    }
    if (OUTBF16) {
        unsigned r0 = (unsigned)cvt_bf16(v[0]) | ((unsigned)cvt_bf16(v[1]) << 16);
        unsigned r1 = (unsigned)cvt_bf16(v[2]) | ((unsigned)cvt_bf16(v[3]) << 16);
        unsigned r2 = (unsigned)cvt_bf16(v[4]) | ((unsigned)cvt_bf16(v[5]) << 16);
        unsigned r3 = (unsigned)cvt_bf16(v[6]) | ((unsigned)cvt_bf16(v[7]) << 16);
        uint4 o = {r0, r1, r2, r3};
        *(uint4*)((unsigned short*)outv + (size_t)node * F + c0) = o;
    } else {
        float4 o0 = {v[0], v[1], v[2], v[3]};
        float4 o1 = {v[4], v[5], v[6], v[7]};
        float* op = (float*)outv + (size_t)node * F + c0;
        *(float4*)op       = o0;
        *(float4*)(op + 4) = o1;
    }
}

extern "C" void kernel_launch(void* const* d_in, const int* in_sizes, int n_in,
                              void* d_out, int out_size, void* d_ws, size_t ws_size,
                              hipStream_t stream)
{
    const float* x      = (const float*)d_in[0];
    const int*   eidx   = (const int*)d_in[1];
    const float* W1     = (const float*)d_in[2];
    const float* a_src1 = (const float*)d_in[3];
    const float* a_dst1 = (const float*)d_in[4];
    const float* b1     = (const float*)d_in[5];
    const float* W2     = (const float*)d_in[6];
    const float* a_src2 = (const float*)d_in[7];
    const float* a_dst2 = (const float*)d_in[8];
    const float* b2     = (const float*)d_in[9];

    const int N = in_sizes[0] / F;
    const int E = in_sizes[1] / 2;
    const int TOT = E + N;
    const int* src = eidx;
    const int* dst = eidx + E;

    const int nbuc = (N + 255) / 256;        // coarse buckets (dst>>8)
    const int nab  = (TOT + ACH - 1) / ACH;  // pass-A blocks
    const int nb   = (N + 1023) / 1024;      // degree-sort blocks

    // workspace layout
    unsigned* epack = (unsigned*)d_ws;                     // TOT
    unsigned short* hbf    = (unsigned short*)(epack + TOT);   // N*F bf16
    unsigned short* out1bf = hbf + (size_t)N * F;          // N*F bf16
    float* as = (float*)(out1bf + (size_t)N * F);          // N*4
    float* ad = as + (size_t)N * NHEADS;                   // N*4
    int* deg    = (int*)(ad + (size_t)N * NHEADS);         // N
    int* rowptr = deg + N;                                 // N+1
    int* ssrc   = rowptr + N + 1;                          // TOT
    int* order  = ssrc + TOT;                              // N
    int* bh     = order + N;                               // nb*256
    int* bha    = bh + (size_t)nb * 256;                   // nab*nbuc
    int* btot   = bha + (size_t)nab * nbuc;                // nbuc
    int* bbase  = btot + nbuc;                             // nbuc+1
    short* Wb1  = (short*)(((uintptr_t)(bbase + nbuc + 1) + 15) & ~(uintptr_t)15);
    short* Wb2  = Wb1 + 36 * 512;

    const int gemmBlocks = (N + 63) / 64;
    const int aggBlocks  = (N + 15) / 16;

    // ---- W pre-pack ----
    k_packW<<<72, 256, 0, stream>>>(W1, a_src1, a_dst1, Wb1);
    k_packW<<<72, 256, 0, stream>>>(W2, a_src2, a_dst2, Wb2);

    // ---- CSR build via coarse buckets ----
    k_bhist<<<nab, 256, 0, stream>>>(src, dst, bha, nbuc, E, TOT);
    k_bscan1<<<(nbuc + 255) / 256, 256, 0, stream>>>(bha, btot, nbuc, nab);
    k_bscan2<<<1, 512, 0, stream>>>(btot, bbase, nbuc);
    k_bscan3<<<(nab * nbuc + 255) / 256, 256, 0, stream>>>(bha, bbase, nbuc, nab * nbuc);
    k_bscatter<<<nab, 256, 0, stream>>>(src, dst, bha, epack, nbuc, E, TOT);
    k_bfinal<<<nbuc, 256, 0, stream>>>(epack, bbase, deg, rowptr, ssrc, N, nbuc);

    // ---- degree sort ----
    k_sort_hist<<<nb, 256, 0, stream>>>(deg, bh, N);
    k_sort_off<<<1, 256, 0, stream>>>(bh, nb);
    k_sort_scatter<<<nb, 256, 0, stream>>>(deg, bh, order, N);

    // ---- layer 1: x (f32) -> out1bf (bf16) ----
    k_gemm_mfma<false><<<gemmBlocks, 256, 0, stream>>>(x, Wb1, hbf, as, ad, N);
    k_aggregate<true><<<aggBlocks, 256, 0, stream>>>(rowptr, ssrc, order, as, ad, hbf, b1, out1bf, N);

    // ---- layer 2: out1bf (bf16) -> d_out (f32) ----
    k_gemm_mfma<true><<<gemmBlocks, 256, 0, stream>>>(out1bf, Wb2, hbf, as, ad, N);
    k_aggregate<false><<<aggBlocks, 256, 0, stream>>>(rowptr, ssrc, order, as, ad, hbf, b2, d_out, N);
}